// Round 6
// baseline (96.872 us; speedup 1.0000x reference)
//
#include <hip/hip_runtime.h>
#include <cstdint>

// y[m][n] = sum_k x[m][k] * (q[n][k] * scale[n]) + bias[n]
// M=32, K=8192, N=8192; q = signed int4 nibbles packed 8 per int32.
// Harness dtype reality (verified round 4): fp16 tensors are FLOAT32 on
// device (inputs and output); b_packed is int32. ws_size ~268 MB.
//
// Round 10: k-split stream-shaped gemm, HARDENED resubmit of R9 (which
// SIGABRT'd with no counters; static audit found no OOB — prime suspect is
// the (256,8) 64-VGPR cap forcing spill->scratch inside the captured graph).
// Changes vs R9: launch_bounds (256,4) (128-reg cap, no spill possible),
// B loads via the R0-proven uint4+u4e pattern. Theory unchanged: R4 showed
// the one-shot fat-WG burst delivers B at ~0.2-0.7 TB/s with all pipes idle;
// 8192 small WGs with 4 turnover generations reshape demand into the
// sustained stream the fill sustains 6.1 TB/s with.
#define M_DIM 32
#define K_DIM 8192
#define N_DIM 8192

typedef _Float16 f16x8 __attribute__((ext_vector_type(8)));
typedef _Float16 f16x2 __attribute__((ext_vector_type(2)));
typedef float    f32x4 __attribute__((ext_vector_type(4)));

__device__ __forceinline__ uint32_t u4e(uint4 v, int t) {
  return (t == 0) ? v.x : (t == 1) ? v.y : (t == 2) ? v.z : v.w;
}

// Magic-bias dequant: dword (8 nibbles) -> 8 exact f16 in [-8,7].
// t_s = ((w>>4s) & 0x000F000F) ^ 0x64086408 = f16x2 {1024+(n_s^8), 1024+(n_{s+4}^8)}
// minus 1032.0 -> {val(n_s), val(n_{s+4})} exactly (integers < 2048, exact f16).
// Fragment element j holds nibble kp[j] = (j>>1) + (j&1)*4; xprep bakes the
// SAME permutation into the A layout, so the MFMA dot is exact.
__device__ __forceinline__ f16x8 dq8(uint32_t w) {
  union { uint32_t u[4]; f16x8 v; } r;
  const uint32_t MASK  = 0x000F000Fu;
  const uint32_t MAGIC = 0x64086408u;                 // f16x2 {1032, 1032}
  const f16x2 magic = __builtin_bit_cast(f16x2, MAGIC);
#pragma unroll
  for (int s = 0; s < 4; ++s) {
    uint32_t t = ((w >> (4 * s)) & MASK) ^ MAGIC;
    f16x2 h = __builtin_bit_cast(f16x2, t) - magic;   // v_pk_add_f16 (neg)
    r.u[s] = __builtin_bit_cast(uint32_t, h);
  }
  return r.v;
}

// -------- x prep: f32 x[32][8192] -> f16 xp[g=k/8][m][8], nibble-pair perm --
// Element j of each 8-group = x[k = g*8 + (j>>1) + (j&1)*4]  (interleave lo/hi).
__global__ __launch_bounds__(256) void xprep_kernel(
    const float* __restrict__ x, uint4* __restrict__ xp) {
  const int T = blockIdx.x * 256 + threadIdx.x;  // 0..32767
  const int m = T >> 10;                         // 0..31
  const int g = T & 1023;                        // 0..1023
  const f32x4* p = (const f32x4*)(x + (size_t)m * K_DIM + (size_t)g * 8);
  f32x4 lo = p[0], hi = p[1];
  union { uint4 q; f16x8 v; } o;
#pragma unroll
  for (int s = 0; s < 4; ++s) {
    o.v[2 * s]     = (_Float16)lo[s];            // nibble-pair perm: {lo_s, hi_s}
    o.v[2 * s + 1] = (_Float16)hi[s];
  }
  xp[(size_t)g * 32 + m] = o.q;
}

// -------- k-split GEMM: 8192 WGs x 256 thr (4 waves) -----------------------
// blockIdx.x = nt*16 + ks; WG tile = n in [nt*16, +16), k in [ks*512, +512).
// Wave w: k in [ks*512 + w*128, +128) -> ONE B-load instr (rows n0+l16,
// uint4 selected by quad = 64 B/row), 4 MFMA k-iters, 2 m-tiles.
// k identity both operands: dword/group index = ks*64 + w*16 + quad*4 + t.
// Partials (pre-scale) to part[ks][m][n] in ws; exact f32, fixed order.
// XCD note: bx%8 == ks%8, so all WGs sharing an xp slice land on one XCD's
// L2 -> A traffic is 2 slices (64 KB) per XCD.
__global__ __launch_bounds__(256, 4) void qgemm_ks(
    const uint32_t* __restrict__ bq,     // packed int4 [N, K/8]
    const uint4*    __restrict__ xp,     // f16 [1024][32][8] (perm'd)
    float*          __restrict__ part) { // f32 [16][32][8192] partials
  __shared__ float red[4][16][33];       // [wave][n][m], ~8.4 KB

  const int tid  = threadIdx.x;
  const int w    = tid >> 6;             // wave 0..3
  const int lane = tid & 63;
  const int l16  = lane & 15;
  const int quad = lane >> 4;
  const int bx   = blockIdx.x;
  const int ks   = bx & 15;              // k-slice 0..15
  const int nt   = bx >> 4;              // n-tile  0..511
  const int n0   = nt << 4;              // 16 n per WG

  // B: one uint4 per lane; uint4 index within row = ks*16 + w*4 + quad.
  const uint4* bq4 = (const uint4*)bq;
  const uint4 b = bq4[(size_t)(n0 + l16) * 256 + (ks << 4) + (w << 2) + quad];

  // A: group base gb = ks*64 + w*16; g = gb + quad*4 + t; index g*32 + m.
  const uint4* ap = xp + (size_t)(((ks << 6) + (w << 4) + (quad << 2)) * 32 + l16);

  f32x4 acc0 = {0.f, 0.f, 0.f, 0.f};    // m 0..15
  f32x4 acc1 = {0.f, 0.f, 0.f, 0.f};    // m 16..31
#pragma unroll
  for (int t = 0; t < 4; ++t) {
    const uint4 a0 = ap[t * 32];
    const uint4 a1 = ap[t * 32 + 16];
    f16x8 fb  = dq8(u4e(b, t));
    f16x8 fa0 = __builtin_bit_cast(f16x8, a0);
    f16x8 fa1 = __builtin_bit_cast(f16x8, a1);
    acc0 = __builtin_amdgcn_mfma_f32_16x16x32_f16(fa0, fb, acc0, 0, 0, 0);
    acc1 = __builtin_amdgcn_mfma_f32_16x16x32_f16(fa1, fb, acc1, 0, 0, 0);
  }

  // C/D layout (verified round 4): n = lane&15, m = quad*4 + r.
#pragma unroll
  for (int r = 0; r < 4; ++r) {
    const int mr = (quad << 2) + r;
    red[w][l16][mr]      = acc0[r];
    red[w][l16][mr + 16] = acc1[r];
  }

  __syncthreads();

  // 256 threads, 512 partial outputs: each takes (n, m) and (n, m+16).
  const int n = tid & 15;
  const int m = tid >> 4;                // 0..15
  float s0 = 0.f, s1 = 0.f;
#pragma unroll
  for (int ww = 0; ww < 4; ++ww) { s0 += red[ww][n][m]; s1 += red[ww][n][m + 16]; }
  const int gn = n0 + n;
  part[((size_t)ks * 32 + m) * N_DIM + gn]      = s0;
  part[((size_t)ks * 32 + m + 16) * N_DIM + gn] = s1;
}

// -------- reduce: y = (sum_ks part) * scale + bias -------------------------
__global__ __launch_bounds__(256) void reduce_ks(
    const float* __restrict__ part,      // f32 [16][32][8192]
    const float* __restrict__ sc,        // f32 [8192]
    const float* __restrict__ bi,        // f32 [8192]
    float*       __restrict__ out) {     // f32 [32][8192]
  const int T  = blockIdx.x * 256 + threadIdx.x;  // 0..65535
  const int m  = T >> 11;                // 0..31
  const int n4 = T & 2047;               // f32x4 index within row
  const f32x4* p = (const f32x4*)part + (size_t)m * 2048 + n4;
  f32x4 s = {0.f, 0.f, 0.f, 0.f};
#pragma unroll
  for (int ks = 0; ks < 16; ++ks) s += p[(size_t)ks * 32 * 2048];
  const f32x4 s4 = ((const f32x4*)sc)[n4];
  const f32x4 b4 = ((const f32x4*)bi)[n4];
  f32x4 r;
#pragma unroll
  for (int i = 0; i < 4; ++i) r[i] = fmaf(s[i], s4[i], b4[i]);
  ((f32x4*)out)[(size_t)m * 2048 + n4] = r;
}

// -------- fallback (tiny ws): round-4 known-good direct kernel -------------
__global__ __launch_bounds__(512) void qgemm_direct(
    const uint32_t* __restrict__ bq, const float* __restrict__ x,
    const float* __restrict__ sc, const float* __restrict__ bi,
    float* __restrict__ out) {
  __shared__ float red[8][32][40];
  const int tid  = threadIdx.x;
  const int w    = tid >> 6;
  const int lane = tid & 63;
  const int l16  = lane & 15;
  const int quad = lane >> 4;
  const int n0   = blockIdx.x << 5;

  const uint4* bq4 = (const uint4*)bq;
  const uint4* bp0 = bq4 + (size_t)(n0 + l16) * 256 + (w << 5) + quad;
  const uint4* bp1 = bp0 + (size_t)16 * 256;
  const float* ap0 = x + (size_t)l16 * K_DIM + (w << 10) + (quad << 5);
  const float* ap1 = ap0 + (size_t)16 * K_DIM;

  f32x4 acc00 = {0.f,0.f,0.f,0.f}, acc01 = {0.f,0.f,0.f,0.f};
  f32x4 acc10 = {0.f,0.f,0.f,0.f}, acc11 = {0.f,0.f,0.f,0.f};
#pragma unroll
  for (int c = 0; c < 8; ++c) {
    const uint4 wb0 = bp0[c * 4];
    const uint4 wb1 = bp1[c * 4];
#pragma unroll
    for (int t = 0; t < 4; ++t) {
      const float* a0 = ap0 + c * 128 + t * 8;
      const float* a1 = ap1 + c * 128 + t * 8;
      f32x4 l0 = *(const f32x4*)a0, h0 = *(const f32x4*)(a0 + 4);
      f32x4 l1 = *(const f32x4*)a1, h1 = *(const f32x4*)(a1 + 4);
      f16x8 fa0, fa1;
#pragma unroll
      for (int s = 0; s < 4; ++s) {
        fa0[2*s] = (_Float16)l0[s]; fa0[2*s+1] = (_Float16)h0[s];
        fa1[2*s] = (_Float16)l1[s]; fa1[2*s+1] = (_Float16)h1[s];
      }
      f16x8 fb0 = dq8(u4e(wb0, t));
      f16x8 fb1 = dq8(u4e(wb1, t));
      acc00 = __builtin_amdgcn_mfma_f32_16x16x32_f16(fa0, fb0, acc00, 0, 0, 0);
      acc01 = __builtin_amdgcn_mfma_f32_16x16x32_f16(fa1, fb0, acc01, 0, 0, 0);
      acc10 = __builtin_amdgcn_mfma_f32_16x16x32_f16(fa0, fb1, acc10, 0, 0, 0);
      acc11 = __builtin_amdgcn_mfma_f32_16x16x32_f16(fa1, fb1, acc11, 0, 0, 0);
    }
  }
#pragma unroll
  for (int r = 0; r < 4; ++r) {
    const int mr = (quad << 2) + r;
    red[w][l16][mr]           = acc00[r];
    red[w][l16][mr + 16]      = acc01[r];
    red[w][l16 + 16][mr]      = acc10[r];
    red[w][l16 + 16][mr + 16] = acc11[r];
  }
  __syncthreads();
  const int n  = tid & 31;
  const int mh = tid >> 5;
  float s0 = 0.f, s1 = 0.f;
#pragma unroll
  for (int ww = 0; ww < 8; ++ww) { s0 += red[ww][n][mh]; s1 += red[ww][n][mh+16]; }
  const int gn = n0 + n;
  out[(size_t)mh * N_DIM + gn]        = fmaf(s0, sc[gn], bi[gn]);
  out[(size_t)(mh + 16) * N_DIM + gn] = fmaf(s1, sc[gn], bi[gn]);
}

extern "C" void kernel_launch(void* const* d_in, const int* in_sizes, int n_in,
                              void* d_out, int out_size, void* d_ws, size_t ws_size,
                              hipStream_t stream) {
  const float*    x  = (const float*)d_in[0];     // f32 [32,8192]
  const uint32_t* bq = (const uint32_t*)d_in[1];  // int32 [8192,1024]
  const float*    sc = (const float*)d_in[2];     // f32 [8192]
  const float*    bi = (const float*)d_in[3];     // f32 [8192]
  float*          y  = (float*)d_out;             // f32 [32,8192]

  const size_t XP_PAD = (size_t)1 << 20;                 // xp region (512 KB used)
  const size_t PART_B = (size_t)16 * 32 * N_DIM * 4;     // 16 MB partials
  if (ws_size >= XP_PAD + PART_B) {                      // constant -> graph-safe
    uint4* xp   = (uint4*)d_ws;
    float* part = (float*)((char*)d_ws + XP_PAD);
    xprep_kernel<<<128, 256, 0, stream>>>(x, xp);
    qgemm_ks<<<8192, 256, 0, stream>>>(bq, xp, part);
    reduce_ks<<<256, 256, 0, stream>>>(part, sc, bi, y);
  } else {
    qgemm_direct<<<N_DIM / 32, 512, 0, stream>>>(bq, x, sc, bi, y);
  }
}

// Round 7
// 89.562 us; speedup vs baseline: 1.0816x; 1.0816x over previous
//
#include <hip/hip_runtime.h>
#include <cstdint>

// y[m][n] = sum_k x[m][k] * (q[n][k] * scale[n]) + bias[n]
// M=32, K=8192, N=8192; q = signed int4 nibbles packed 8 per int32.
// Harness dtype reality (verified round 4): fp16 tensors are FLOAT32 on
// device (inputs and output); b_packed is int32. ws_size ~268 MB.
//
// Round 11: EXACT revert to the session champion (87.4 us best-measured;
// 89.2 re-benched). Seven structural families tried (fused gather, 2x
// occupancy, nt loads, fused LDS-stage, k-split turnover) all land at
// 91.7-117.8 — the timed region is dominated by a harness-fixed floor
// (268 MB ws re-poison @ ~44 us + reset()'s memset/restore nodes), and the
// controllable gemm span (~10-20 us) is near its HBM-latency floor. The
// champion's 2-dispatch xp structure is the best-measured configuration.
#define M_DIM 32
#define K_DIM 8192
#define N_DIM 8192

typedef _Float16 f16x8 __attribute__((ext_vector_type(8)));
typedef _Float16 f16x2 __attribute__((ext_vector_type(2)));
typedef float    f32x4 __attribute__((ext_vector_type(4)));

__device__ __forceinline__ uint32_t u4e(uint4 v, int t) {
  return (t == 0) ? v.x : (t == 1) ? v.y : (t == 2) ? v.z : v.w;
}

// Magic-bias dequant: dword (8 nibbles) -> 8 exact f16 in [-8,7].
// t_s = ((w>>4s) & 0x000F000F) ^ 0x64086408 = f16x2 {1024+(n_s^8), 1024+(n_{s+4}^8)}
// minus 1032.0 -> {val(n_s), val(n_{s+4})} exactly (integers < 2048, exact f16).
// Fragment element j therefore holds nibble kp[j] = (j>>1) + (j&1)*4; xprep
// bakes the SAME permutation into the A layout, so the MFMA dot is exact.
// ~15 VALU/dword vs ~36 for shift-decode.
__device__ __forceinline__ f16x8 dq8(uint32_t w) {
  union { uint32_t u[4]; f16x8 v; } r;
  const uint32_t MASK  = 0x000F000Fu;
  const uint32_t MAGIC = 0x64086408u;                 // f16x2 {1032, 1032}
  const f16x2 magic = __builtin_bit_cast(f16x2, MAGIC);
#pragma unroll
  for (int s = 0; s < 4; ++s) {
    uint32_t t = ((w >> (4 * s)) & MASK) ^ MAGIC;
    f16x2 h = __builtin_bit_cast(f16x2, t) - magic;   // v_pk_add_f16 (neg)
    r.u[s] = __builtin_bit_cast(uint32_t, h);
  }
  return r.v;
}

// -------- x prep: f32 x[32][8192] -> f16 xp[g=k/8][m][8], nibble-pair perm --
// Element j of each 8-group = x[k = g*8 + (j>>1) + (j&1)*4]  (interleave lo/hi).
__global__ __launch_bounds__(256) void xprep_kernel(
    const float* __restrict__ x, uint4* __restrict__ xp) {
  const int T = blockIdx.x * 256 + threadIdx.x;  // 0..32767
  const int m = T >> 10;                         // 0..31
  const int g = T & 1023;                        // 0..1023
  const f32x4* p = (const f32x4*)(x + (size_t)m * K_DIM + (size_t)g * 8);
  f32x4 lo = p[0], hi = p[1];
  union { uint4 q; f16x8 v; } o;
#pragma unroll
  for (int s = 0; s < 4; ++s) {
    o.v[2 * s]     = (_Float16)lo[s];            // nibble-pair perm: {lo_s, hi_s}
    o.v[2 * s + 1] = (_Float16)hi[s];
  }
  xp[(size_t)g * 32 + m] = o.q;
}

// -------- main GEMM: 256 WGs x 1024 thr (16 waves) -------------------------
// WG = 32 cols (n) x 32 rows (m); 16 waves k-split (512 k each).
// All 8 B uint4 prefetched up front (whole WG HBM demand in flight at t=0);
// A ping-pong by t-group (4 uint4 live -> no VGPR spill at the 128 cap).
// k-scramble: slot (c,t,quad,j) takes k = (w*64+c*16+quad*4+t)*8 + kp[j]
// from BOTH operands — same bijection, exact dot product.
__global__ __launch_bounds__(1024, 4) void qgemm_xp(
    const uint32_t* __restrict__ bq,     // packed int4 [N, K/8]
    const uint4*    __restrict__ xp,     // f16 [1024][32][8] (perm'd)
    const float*    __restrict__ sc,     // f32 [8192]
    const float*    __restrict__ bi,     // f32 [8192]
    float*          __restrict__ out) {  // f32 [32, 8192]
  __shared__ float red[16][32][33];      // [wave][n][m], stride 33 (66 KB)

  const int tid  = threadIdx.x;
  const int w    = tid >> 6;             // wave 0..15 -> k0 = w*512
  const int lane = tid & 63;
  const int l16  = lane & 15;
  const int quad = lane >> 4;
  const int n0   = blockIdx.x << 5;      // 32 n per WG

  // B uint4 index: row*256 + w*16 + c*4 + quad; rows n0+l16, n0+l16+16
  const uint4* bq4 = (const uint4*)bq;
  const uint4* bp0 = bq4 + (size_t)(n0 + l16) * 256 + (w << 4) + quad;
  const uint4* bp1 = bp0 + (size_t)16 * 256;
  // A uint4 index: g*32 + m; g = w*64 + quad*4 + c*16 + t; m = l16 (+16)
  const uint4* ap  = xp + (size_t)(((w << 6) + (quad << 2)) * 32 + l16);

  // Prefetch ALL B: 4 chunks x 2 n-tiles = 8 outstanding HBM loads.
  uint4 b0[4], b1[4];
#pragma unroll
  for (int c = 0; c < 4; ++c) { b0[c] = bp0[c * 4]; b1[c] = bp1[c * 4]; }

  f32x4 acc00 = {0.f, 0.f, 0.f, 0.f};
  f32x4 acc01 = {0.f, 0.f, 0.f, 0.f};
  f32x4 acc10 = {0.f, 0.f, 0.f, 0.f};
  f32x4 acc11 = {0.f, 0.f, 0.f, 0.f};

  // A ping-pong over 16 t-groups; group g' -> uint4 offset ((g'>>2)*16+(g'&3))*32.
  uint4 a0c = ap[0], a1c = ap[16];       // group 0, both m-tiles
#pragma unroll
  for (int g = 0; g < 16; ++g) {
    const int gn  = (g + 1) & 15;        // last iter refetches group 0 (harmless)
    const int off = (((gn >> 2) * 16) + (gn & 3)) * 32;
    uint4 a0n = ap[off];
    uint4 a1n = ap[off + 16];

    const int c = g >> 2, t = g & 3;
    f16x8 fb0 = dq8(u4e(b0[c], t));
    f16x8 fb1 = dq8(u4e(b1[c], t));
    f16x8 fa0 = __builtin_bit_cast(f16x8, a0c);
    f16x8 fa1 = __builtin_bit_cast(f16x8, a1c);
    acc00 = __builtin_amdgcn_mfma_f32_16x16x32_f16(fa0, fb0, acc00, 0, 0, 0);
    acc01 = __builtin_amdgcn_mfma_f32_16x16x32_f16(fa1, fb0, acc01, 0, 0, 0);
    acc10 = __builtin_amdgcn_mfma_f32_16x16x32_f16(fa0, fb1, acc10, 0, 0, 0);
    acc11 = __builtin_amdgcn_mfma_f32_16x16x32_f16(fa1, fb1, acc11, 0, 0, 0);

    a0c = a0n; a1c = a1n;                // renamed away by full unroll
  }

  // C/D layout (verified round 4): n = lane&15, m = quad*4 + r.
#pragma unroll
  for (int r = 0; r < 4; ++r) {
    const int mr = (quad << 2) + r;
    red[w][l16][mr]           = acc00[r];
    red[w][l16][mr + 16]      = acc01[r];
    red[w][l16 + 16][mr]      = acc10[r];
    red[w][l16 + 16][mr + 16] = acc11[r];
  }

  __syncthreads();

  // 1024 threads = one output each: n = tid&31, m = tid>>5; stride-33 rows
  // make the 16-way read conflict-free across lanes.
  const int n = tid & 31;
  const int m = tid >> 5;
  float s = 0.f;
#pragma unroll
  for (int ww = 0; ww < 16; ++ww) s += red[ww][n][m];
  const int gn = n0 + n;
  out[(size_t)m * N_DIM + gn] = fmaf(s, sc[gn], bi[gn]);
}

// -------- fallback (tiny ws): round-4 known-good direct kernel -------------
__global__ __launch_bounds__(512) void qgemm_direct(
    const uint32_t* __restrict__ bq, const float* __restrict__ x,
    const float* __restrict__ sc, const float* __restrict__ bi,
    float* __restrict__ out) {
  __shared__ float red[8][32][40];
  const int tid  = threadIdx.x;
  const int w    = tid >> 6;
  const int lane = tid & 63;
  const int l16  = lane & 15;
  const int quad = lane >> 4;
  const int n0   = blockIdx.x << 5;

  const uint4* bq4 = (const uint4*)bq;
  const uint4* bp0 = bq4 + (size_t)(n0 + l16) * 256 + (w << 5) + quad;
  const uint4* bp1 = bp0 + (size_t)16 * 256;
  const float* ap0 = x + (size_t)l16 * K_DIM + (w << 10) + (quad << 5);
  const float* ap1 = ap0 + (size_t)16 * K_DIM;

  f32x4 acc00 = {0.f,0.f,0.f,0.f}, acc01 = {0.f,0.f,0.f,0.f};
  f32x4 acc10 = {0.f,0.f,0.f,0.f}, acc11 = {0.f,0.f,0.f,0.f};
#pragma unroll
  for (int c = 0; c < 8; ++c) {
    const uint4 wb0 = bp0[c * 4];
    const uint4 wb1 = bp1[c * 4];
#pragma unroll
    for (int t = 0; t < 4; ++t) {
      const float* a0 = ap0 + c * 128 + t * 8;
      const float* a1 = ap1 + c * 128 + t * 8;
      f32x4 l0 = *(const f32x4*)a0, h0 = *(const f32x4*)(a0 + 4);
      f32x4 l1 = *(const f32x4*)a1, h1 = *(const f32x4*)(a1 + 4);
      f16x8 fa0, fa1;
#pragma unroll
      for (int s = 0; s < 4; ++s) {
        fa0[2*s] = (_Float16)l0[s]; fa0[2*s+1] = (_Float16)h0[s];
        fa1[2*s] = (_Float16)l1[s]; fa1[2*s+1] = (_Float16)h1[s];
      }
      f16x8 fb0 = dq8(u4e(wb0, t));
      f16x8 fb1 = dq8(u4e(wb1, t));
      acc00 = __builtin_amdgcn_mfma_f32_16x16x32_f16(fa0, fb0, acc00, 0, 0, 0);
      acc01 = __builtin_amdgcn_mfma_f32_16x16x32_f16(fa1, fb0, acc01, 0, 0, 0);
      acc10 = __builtin_amdgcn_mfma_f32_16x16x32_f16(fa0, fb1, acc10, 0, 0, 0);
      acc11 = __builtin_amdgcn_mfma_f32_16x16x32_f16(fa1, fb1, acc11, 0, 0, 0);
    }
  }
#pragma unroll
  for (int r = 0; r < 4; ++r) {
    const int mr = (quad << 2) + r;
    red[w][l16][mr]           = acc00[r];
    red[w][l16][mr + 16]      = acc01[r];
    red[w][l16 + 16][mr]      = acc10[r];
    red[w][l16 + 16][mr + 16] = acc11[r];
  }
  __syncthreads();
  const int n  = tid & 31;
  const int mh = tid >> 5;
  float s0 = 0.f, s1 = 0.f;
#pragma unroll
  for (int ww = 0; ww < 8; ++ww) { s0 += red[ww][n][mh]; s1 += red[ww][n][mh+16]; }
  const int gn = n0 + n;
  out[(size_t)mh * N_DIM + gn]        = fmaf(s0, sc[gn], bi[gn]);
  out[(size_t)(mh + 16) * N_DIM + gn] = fmaf(s1, sc[gn], bi[gn]);
}

extern "C" void kernel_launch(void* const* d_in, const int* in_sizes, int n_in,
                              void* d_out, int out_size, void* d_ws, size_t ws_size,
                              hipStream_t stream) {
  const float*    x  = (const float*)d_in[0];     // f32 [32,8192]
  const uint32_t* bq = (const uint32_t*)d_in[1];  // int32 [8192,1024]
  const float*    sc = (const float*)d_in[2];     // f32 [8192]
  const float*    bi = (const float*)d_in[3];     // f32 [8192]
  float*          y  = (float*)d_out;             // f32 [32,8192]

  const size_t XP_BYTES = (size_t)M_DIM * K_DIM * 2;  // 512 KB f16
  if (ws_size >= XP_BYTES) {                          // constant -> graph-safe
    uint4* xp = (uint4*)d_ws;
    xprep_kernel<<<128, 256, 0, stream>>>(x, xp);
    qgemm_xp<<<N_DIM / 32, 1024, 0, stream>>>(bq, xp, sc, bi, y);
  } else {
    qgemm_direct<<<N_DIM / 32, 512, 0, stream>>>(bq, x, sc, bi, y);
  }
}